// Round 5
// baseline (215.498 us; speedup 1.0000x reference)
//
#include <hip/hip_runtime.h>
#include <hip/hip_bf16.h>
#include <math.h>

#define BATCH 4
#define SEQ   4096
#define DIM   256
#define AS1 __attribute__((address_space(1)))
#define AS3 __attribute__((address_space(3)))

typedef __attribute__((ext_vector_type(8))) short  bf16x8;
typedef __attribute__((ext_vector_type(4))) short  bf16x4;
typedef __attribute__((ext_vector_type(4))) float  f32x4;
typedef __attribute__((ext_vector_type(4))) int    i32x4;

__device__ __forceinline__ short f2bf(float f) {
    union { float f; unsigned u; } v; v.f = f;
    unsigned r = (v.u + 0x7fffu + ((v.u >> 16) & 1u)) >> 16;
    return (short)r;
}

__device__ __forceinline__ void gload_lds16(const void* g, void* l) {
    __builtin_amdgcn_global_load_lds((const AS1 void*)g, (AS3 void*)l, 16, 0, 0);
}

// ---------------------------------------------------------------------------
// Projection: out[n][e] = (sum_d A[n][d]*W[e][d] + bias[e]) * scale  (bf16)
// TRANS=true stores out^T per batch ([b][256][4096]).
// ---------------------------------------------------------------------------
template<bool TRANS>
__global__ __launch_bounds__(256) void proj_kernel(
    const float* __restrict__ A,
    const float* __restrict__ W,
    const float* __restrict__ bias,
    unsigned short* __restrict__ out,
    float scale)
{
    __shared__ __align__(16) short Wlds[256 * 40];

    const int t    = threadIdx.x;
    const int wave = t >> 6, lane = t & 63;
    const int c    = lane & 15, g = lane >> 4;
    const int wrow = blockIdx.x * 64 + wave * 16;

    f32x4 acc[16];
    for (int nt = 0; nt < 16; ++nt) acc[nt] = f32x4{0.f, 0.f, 0.f, 0.f};

    f32x4 wpf[8];
    for (int i = 0; i < 8; ++i) {
        int f = i * 1024 + t * 4;
        wpf[i] = *(const f32x4*)&W[(f >> 5) * 256 + (f & 31)];
    }
    f32x4 a0 = *(const f32x4*)&A[(wrow + c) * 256 + g * 8];
    f32x4 a1 = *(const f32x4*)&A[(wrow + c) * 256 + g * 8 + 4];

    for (int ks = 0; ks < 8; ++ks) {
        __syncthreads();
        for (int i = 0; i < 8; ++i) {
            int f = i * 1024 + t * 4;
            bf16x4 s4;
            s4[0] = f2bf(wpf[i][0]); s4[1] = f2bf(wpf[i][1]);
            s4[2] = f2bf(wpf[i][2]); s4[3] = f2bf(wpf[i][3]);
            *(bf16x4*)&Wlds[(f >> 5) * 40 + (f & 31)] = s4;
        }
        __syncthreads();
        bf16x8 af;
        af[0] = f2bf(a0[0]); af[1] = f2bf(a0[1]); af[2] = f2bf(a0[2]); af[3] = f2bf(a0[3]);
        af[4] = f2bf(a1[0]); af[5] = f2bf(a1[1]); af[6] = f2bf(a1[2]); af[7] = f2bf(a1[3]);
        if (ks < 7) {
            for (int i = 0; i < 8; ++i) {
                int f = i * 1024 + t * 4;
                wpf[i] = *(const f32x4*)&W[(f >> 5) * 256 + (ks + 1) * 32 + (f & 31)];
            }
            a0 = *(const f32x4*)&A[(wrow + c) * 256 + (ks + 1) * 32 + g * 8];
            a1 = *(const f32x4*)&A[(wrow + c) * 256 + (ks + 1) * 32 + g * 8 + 4];
        }
        __builtin_amdgcn_s_setprio(1);
        for (int nt = 0; nt < 16; ++nt) {
            bf16x8 bfr = *(const bf16x8*)&Wlds[(nt * 16 + c) * 40 + g * 8];
            acc[nt] = __builtin_amdgcn_mfma_f32_16x16x32_bf16(af, bfr, acc[nt], 0, 0, 0);
        }
        __builtin_amdgcn_s_setprio(0);
    }

    if constexpr (TRANS) {
        const int nb = wrow >> 12, n0 = wrow & 4095;
        for (int nt = 0; nt < 16; ++nt) {
            float bv = bias[nt * 16 + c];
            bf16x4 s4;
            s4[0] = f2bf((acc[nt][0] + bv) * scale); s4[1] = f2bf((acc[nt][1] + bv) * scale);
            s4[2] = f2bf((acc[nt][2] + bv) * scale); s4[3] = f2bf((acc[nt][3] + bv) * scale);
            *(bf16x4*)&out[((size_t)nb * DIM + nt * 16 + c) * SEQ + n0 + g * 4] = s4;
        }
    } else {
        for (int nt = 0; nt < 16; ++nt) {
            float bv = bias[nt * 16 + c];
            for (int j = 0; j < 4; ++j)
                out[(size_t)(wrow + g * 4 + j) * 256 + nt * 16 + c] =
                    (unsigned short)f2bf((acc[nt][j] + bv) * scale);
        }
    }
}

// ---------------------------------------------------------------------------
// Flash attention. 4 waves x 32 q-rows = 128 q-rows/block. KVB=32.
// K/V fragments reused across 2 q-row-tiles (2x arithmetic intensity).
// gload_lds staging (pre-swizzled source), dbuf + counted vmcnt(8), defer-max.
// Q comes in pre-scaled by 1/sqrt(D) (folded into projection).
// ---------------------------------------------------------------------------
#define KVB  32
#define PROW 40

__global__ __launch_bounds__(256, 2) void fa2_kernel(
    const unsigned short* __restrict__ Q,   // [4][4096][256] bf16 (pre-scaled)
    const unsigned short* __restrict__ K,   // [4][4096][256] bf16
    const unsigned short* __restrict__ Vt,  // [4][256][4096] bf16
    float* __restrict__ Opart,              // [nsplit][4][4096][256] f32 (l-normalized)
    float2* __restrict__ ml,                // [nsplit][4*4096]
    int nsplit)
{
    __shared__ __align__(16) unsigned short Klds[2][KVB * 256];   // 2 x 16 KB
    __shared__ __align__(16) unsigned short Vlds[2][256 * KVB];   // 2 x 16 KB
    __shared__ __align__(16) unsigned short Plds[4][32 * PROW];   // 10240 B

    const int t = threadIdx.x;
    const int w = t >> 6, lane = t & 63;
    const int c = lane & 15, g = lane >> 4;

    int b, sidx, qt;
    if (nsplit == 4) {
        int xcd  = blockIdx.x & 7;
        int rest = blockIdx.x >> 3;            // 0..63
        int combo = (xcd << 1) | (rest >> 5);  // 0..15 ; 2 combos per XCD
        qt   = rest & 31;
        b    = combo >> 2;
        sidx = combo & 3;
    } else {
        qt   = blockIdx.x & 31;
        b    = blockIdx.x >> 5;
        sidx = 0;
    }
    const int ts = (sidx * 128) / nsplit;
    const int te = ((sidx + 1) * 128) / nsplit;

    const int wrow = qt * 128 + w * 32;   // this wave's 32 q-rows

    // Q fragments: qf[h][ks] for q-row-tile h (rows wrow+h*16 .. +15)
    bf16x8 qf[2][8];
    #pragma unroll
    for (int h = 0; h < 2; ++h) {
        const unsigned short* Qrow = &Q[((size_t)b * SEQ + wrow + h * 16 + c) * DIM];
        #pragma unroll
        for (int ks = 0; ks < 8; ++ks)
            qf[h][ks] = *(const bf16x8*)&Qrow[ks * 32 + g * 8];
    }

    f32x4 o[2][16];
    #pragma unroll
    for (int h = 0; h < 2; ++h)
        #pragma unroll
        for (int nt = 0; nt < 16; ++nt) o[h][nt] = f32x4{0.f, 0.f, 0.f, 0.f};
    float m[2][4], llane[2][4];
    #pragma unroll
    for (int h = 0; h < 2; ++h)
        #pragma unroll
        for (int j = 0; j < 4; ++j) { m[h][j] = -1e30f; llane[h][j] = 0.f; }

    const char* Kb_ = (const char*)&K[(size_t)b * SEQ * DIM];
    const char* Vb_ = (const char*)&Vt[(size_t)b * DIM * SEQ];

    // Staging: 16 x 1KB DMA calls per tile for K and V; wave w does calls
    // 4w..4w+3 of each. LDS dest linear; source carries the inverse swizzle.
    const int l31 = lane & 31;
    int koff[4], voff[4], dstb[4];
    const int vsw   = ((lane >> 2) & 3) ^ ((lane >> 4) & 3);
    const int vcb   = ((lane & 3) ^ vsw) << 4;
    #pragma unroll
    for (int ii = 0; ii < 4; ++ii) {
        int kr = 8 * w + 2 * ii + (lane >> 5);
        koff[ii] = kr * 512 + ((l31 ^ (kr & 7)) << 4);
        int vr = 64 * w + 16 * ii + (lane >> 2);
        voff[ii] = vr * (SEQ * 2) + vcb;
        dstb[ii] = (4 * w + ii) * 1024;
    }

    #define STAGE(kt_, buf_) do {                                              \
        const size_t kb_ = (size_t)(kt_) * (KVB * DIM * 2);                    \
        const size_t vb_ = (size_t)(kt_) * (KVB * 2);                          \
        _Pragma("unroll")                                                      \
        for (int ii = 0; ii < 4; ++ii) {                                       \
            gload_lds16(Kb_ + kb_ + koff[ii], (char*)&Klds[buf_][0] + dstb[ii]); \
            gload_lds16(Vb_ + vb_ + voff[ii], (char*)&Vlds[buf_][0] + dstb[ii]); \
        }                                                                      \
    } while (0)

    STAGE(ts, 0);
    int buf = 0;

    const int xk   = (c & 7) << 3;
    const int vcol = (g * 8) ^ ((((c & 3) ^ ((c >> 2) & 3))) << 3);
    unsigned short* Pw = &Plds[w][0];

    for (int kt = ts; kt < te; ++kt) {
        __builtin_amdgcn_s_barrier();   // all waves done reading buf^1
        if (kt + 1 < te) {
            STAGE(kt + 1, buf ^ 1);
            asm volatile("s_waitcnt vmcnt(8)" ::: "memory");  // tile kt landed
        } else {
            asm volatile("s_waitcnt vmcnt(0)" ::: "memory");
        }
        __builtin_amdgcn_s_barrier();   // tile kt visible to all waves

        const unsigned short* Kl = &Klds[buf][0];
        const unsigned short* Vl = &Vlds[buf][0];

        // S = Q K^T : kf fragments reused across both q-row-tiles
        f32x4 s[2][2];
        #pragma unroll
        for (int h = 0; h < 2; ++h) { s[h][0] = f32x4{0.f,0.f,0.f,0.f}; s[h][1] = f32x4{0.f,0.f,0.f,0.f}; }
        __builtin_amdgcn_s_setprio(1);
        #pragma unroll
        for (int ks = 0; ks < 8; ++ks) {
            int off = (ks * 32 + g * 8) ^ xk;
            bf16x8 kf0 = *(const bf16x8*)&Kl[c * 256 + off];
            s[0][0] = __builtin_amdgcn_mfma_f32_16x16x32_bf16(qf[0][ks], kf0, s[0][0], 0, 0, 0);
            s[1][0] = __builtin_amdgcn_mfma_f32_16x16x32_bf16(qf[1][ks], kf0, s[1][0], 0, 0, 0);
            bf16x8 kf1 = *(const bf16x8*)&Kl[(16 + c) * 256 + off];
            s[0][1] = __builtin_amdgcn_mfma_f32_16x16x32_bf16(qf[0][ks], kf1, s[0][1], 0, 0, 0);
            s[1][1] = __builtin_amdgcn_mfma_f32_16x16x32_bf16(qf[1][ks], kf1, s[1][1], 0, 0, 0);
        }
        __builtin_amdgcn_s_setprio(0);

        // defer-max online softmax (no shuffles on the common path)
        float pm[2][4];
        bool ok = true;
        #pragma unroll
        for (int h = 0; h < 2; ++h)
            #pragma unroll
            for (int j = 0; j < 4; ++j) {
                pm[h][j] = fmaxf(s[h][0][j], s[h][1][j]);
                ok = ok && (pm[h][j] <= m[h][j] + 8.f);
            }
        if (!__all(ok)) {
            #pragma unroll
            for (int h = 0; h < 2; ++h) {
                float scj[4];
                #pragma unroll
                for (int j = 0; j < 4; ++j) {
                    float pr = pm[h][j];
                    for (int d = 1; d < 16; d <<= 1) pr = fmaxf(pr, __shfl_xor(pr, d));
                    float mn = fmaxf(m[h][j], pr);
                    float r  = __expf(m[h][j] - mn);
                    m[h][j] = mn; llane[h][j] *= r; scj[j] = r;
                }
                #pragma unroll
                for (int nt = 0; nt < 16; ++nt) {
                    o[h][nt][0] *= scj[0]; o[h][nt][1] *= scj[1];
                    o[h][nt][2] *= scj[2]; o[h][nt][3] *= scj[3];
                }
            }
        }
        #pragma unroll
        for (int h = 0; h < 2; ++h)
            #pragma unroll
            for (int j = 0; j < 4; ++j) {
                float p0 = __expf(s[h][0][j] - m[h][j]);
                float p1 = __expf(s[h][1][j] - m[h][j]);
                llane[h][j] += p0 + p1;
                int prow = h * 16 + g * 4 + j;
                Pw[prow * PROW + c]      = (unsigned short)f2bf(p0);
                Pw[prow * PROW + 16 + c] = (unsigned short)f2bf(p1);
            }

        // PV: O[32][256] += P[32][32] @ V[32][256], vf reused across h
        bf16x8 pa0 = *(const bf16x8*)&Pw[c * PROW + g * 8];
        bf16x8 pa1 = *(const bf16x8*)&Pw[(16 + c) * PROW + g * 8];
        __builtin_amdgcn_s_setprio(1);
        #pragma unroll
        for (int nt = 0; nt < 16; ++nt) {
            bf16x8 vf = *(const bf16x8*)&Vl[(nt * 16 + c) * 32 + vcol];
            o[0][nt] = __builtin_amdgcn_mfma_f32_16x16x32_bf16(pa0, vf, o[0][nt], 0, 0, 0);
            o[1][nt] = __builtin_amdgcn_mfma_f32_16x16x32_bf16(pa1, vf, o[1][nt], 0, 0, 0);
        }
        __builtin_amdgcn_s_setprio(0);
        buf ^= 1;
    }

    // epilogue
    float inv[2][4];
    #pragma unroll
    for (int h = 0; h < 2; ++h)
        #pragma unroll
        for (int j = 0; j < 4; ++j) {
            float v = llane[h][j];
            for (int d = 1; d < 16; d <<= 1) v += __shfl_xor(v, d);
            llane[h][j] = v;
            inv[h][j] = 1.0f / v;
        }
    const size_t obase = ((size_t)sidx * BATCH * SEQ + (size_t)b * SEQ + wrow) * DIM;
    #pragma unroll
    for (int h = 0; h < 2; ++h)
        for (int nt = 0; nt < 16; ++nt)
            #pragma unroll
            for (int j = 0; j < 4; ++j)
                Opart[obase + (size_t)(h * 16 + g * 4 + j) * DIM + nt * 16 + c] =
                    o[h][nt][j] * inv[h][j];
    if (c == 0) {
        #pragma unroll
        for (int h = 0; h < 2; ++h)
            #pragma unroll
            for (int j = 0; j < 4; ++j)
                ml[(size_t)sidx * BATCH * SEQ + (size_t)b * SEQ + wrow + h * 16 + g * 4 + j] =
                    make_float2(m[h][j], llane[h][j]);
    }
}

// ---------------------------------------------------------------------------
// Combine 4 KV-split partials
// ---------------------------------------------------------------------------
__global__ __launch_bounds__(256) void combine_kernel(
    const float* __restrict__ Opart, const float2* __restrict__ ml,
    float* __restrict__ out)
{
    const int t = threadIdx.x;
    const size_t row = (size_t)blockIdx.x * 4 + (t >> 6);
    const int lane = t & 63;

    float2 e[4];
    float M = -1e30f;
    for (int s = 0; s < 4; ++s) {
        e[s] = ml[(size_t)s * BATCH * SEQ + row];
        M = fmaxf(M, e[s].x);
    }
    float wgt[4], L = 0.f;
    for (int s = 0; s < 4; ++s) { wgt[s] = e[s].y * __expf(e[s].x - M); L += wgt[s]; }
    float invL = 1.0f / L;

    f32x4 acc = f32x4{0.f, 0.f, 0.f, 0.f};
    for (int s = 0; s < 4; ++s) {
        f32x4 v = *(const f32x4*)&Opart[((size_t)s * BATCH * SEQ + row) * DIM + lane * 4];
        float ws = wgt[s] * invL;
        acc[0] += ws * v[0]; acc[1] += ws * v[1];
        acc[2] += ws * v[2]; acc[3] += ws * v[3];
    }
    *(f32x4*)&out[row * DIM + lane * 4] = acc;
}

// ---------------------------------------------------------------------------
extern "C" void kernel_launch(void* const* d_in, const int* in_sizes, int n_in,
                              void* d_out, int out_size, void* d_ws, size_t ws_size,
                              hipStream_t stream) {
    const float* x  = (const float*)d_in[0];
    const float* z  = (const float*)d_in[1];
    const float* Wq = (const float*)d_in[2];
    const float* bq = (const float*)d_in[3];
    const float* Wk = (const float*)d_in[4];
    const float* bk = (const float*)d_in[5];
    const float* Wv = (const float*)d_in[6];
    const float* bv = (const float*)d_in[7];
    float* out = (float*)d_out;

    const size_t TENS = (size_t)BATCH * SEQ * DIM;
    unsigned short* Qb  = (unsigned short*)d_ws;
    unsigned short* Kb  = Qb + TENS;
    unsigned short* Vtb = Kb + TENS;

    const size_t base_bytes = 3 * TENS * sizeof(unsigned short);       // 24 MB
    const size_t need4 = base_bytes + 4 * TENS * sizeof(float)         // 64 MB
                       + 4 * (size_t)BATCH * SEQ * sizeof(float2);
    const int nsplit = (ws_size >= need4) ? 4 : 1;

    proj_kernel<false><<<256, 256, 0, stream>>>(x, Wq, bq, Qb, 0.0625f);
    proj_kernel<false><<<256, 256, 0, stream>>>(z, Wk, bk, Kb, 1.0f);
    proj_kernel<true ><<<256, 256, 0, stream>>>(z, Wv, bv, Vtb, 1.0f);

    if (nsplit == 4) {
        float*  Op  = (float*)((char*)d_ws + base_bytes);
        float2* mlb = (float2*)((char*)d_ws + base_bytes + 4 * TENS * sizeof(float));
        fa2_kernel<<<512, 256, 0, stream>>>(Qb, Kb, Vtb, Op, mlb, 4);
        combine_kernel<<<4096, 256, 0, stream>>>(Op, mlb, out);
    } else {
        float2* mlb = (float2*)((char*)d_ws + base_bytes);
        fa2_kernel<<<128, 256, 0, stream>>>(Qb, Kb, Vtb, out, mlb, 1);
    }
}